// Round 8
// baseline (608.537 us; speedup 1.0000x reference)
//
#include <hip/hip_runtime.h>
#include <hip/hip_bf16.h>
#include <stdint.h>

#define B_ 16
#define N_ 64
#define S_ 4096
#define C_ 384
#define H_ 6
#define DH_ 64
#define SCALE_ 0.125f
#define TAU_ 6e-3f
#define LISTCAP 262144

typedef __attribute__((ext_vector_type(8))) _Float16 f16x8;
typedef __attribute__((ext_vector_type(4))) float f32x4;

static __device__ __forceinline__ unsigned short f2h(float x) {
    union { _Float16 h; unsigned short s; } v; v.h = (_Float16)x; return v.s;
}
static __device__ __forceinline__ float h2f_lo(unsigned u) {
    union { unsigned short s; _Float16 h; } v; v.s = (unsigned short)(u & 0xFFFFu); return (float)v.h;
}
static __device__ __forceinline__ float h2f_hi(unsigned u) {
    union { unsigned short s; _Float16 h; } v; v.s = (unsigned short)(u >> 16); return (float)v.h;
}

// async global->LDS, 16B/lane; LDS dest = wave-uniform base + lane*16
static __device__ __forceinline__ void gl_lds16(const void* g, void* l) {
    __builtin_amdgcn_global_load_lds(
        (const __attribute__((address_space(1))) unsigned int*)g,
        (__attribute__((address_space(3))) unsigned int*)l, 16, 0, 0);
}

// ---------------------------------------------------------------------------
// K0: prep — key -> kh (f16, round-to-nearest). Half the writes of round 7.
// ---------------------------------------------------------------------------
__global__ __launch_bounds__(256) void prep_kernel(const float* __restrict__ key,
                                                   unsigned short* __restrict__ kh) {
    size_t gid = (size_t)blockIdx.x * 256 + threadIdx.x;
    size_t base = gid * 8;
    float4 x0 = *(const float4*)(key + base);
    float4 x1 = *(const float4*)(key + base + 4);
    float xs[8] = { x0.x, x0.y, x0.z, x0.w, x1.x, x1.y, x1.z, x1.w };
    unsigned short h[8];
#pragma unroll
    for (int i = 0; i < 8; ++i) h[i] = f2h(xs[i]);
    *(f16x8*)(kh + base) = *(f16x8*)h;
}

// ---------------------------------------------------------------------------
// K1: fused q-proj + qk (fp32 exact) + f16 cast of qk
// ---------------------------------------------------------------------------
__global__ __launch_bounds__(384) void qk_fused_kernel(const float* __restrict__ query,
                                                       const float* __restrict__ Wq,
                                                       const float* __restrict__ Wk,
                                                       float* __restrict__ qk,
                                                       unsigned short* __restrict__ qkh) {
    __shared__ float qstage[4][C_];
    __shared__ float qrow[4][C_];
    int ng = blockIdx.x, b = blockIdx.y;
    int t = threadIdx.x;
    int n0 = ng * 4;
#pragma unroll
    for (int i = 0; i < 4; ++i)
        qstage[i][t] = query[((size_t)(b * N_ + n0 + i)) * C_ + t];
    __syncthreads();
    {
        float a[4];
#pragma unroll
        for (int i = 0; i < 4; ++i) a[i] = 0.f;
        const float4* wq = (const float4*)(Wq + (size_t)t * C_);
        for (int c4 = 0; c4 < C_ / 4; ++c4) {
            float4 w = wq[c4];
#pragma unroll
            for (int i = 0; i < 4; ++i)
                a[i] += qstage[i][c4 * 4 + 0] * w.x + qstage[i][c4 * 4 + 1] * w.y
                      + qstage[i][c4 * 4 + 2] * w.z + qstage[i][c4 * 4 + 3] * w.w;
        }
#pragma unroll
        for (int i = 0; i < 4; ++i) qrow[i][t] = a[i] * SCALE_;
    }
    __syncthreads();
    for (int h = 0; h < H_; ++h) {
        float a[4];
#pragma unroll
        for (int i = 0; i < 4; ++i) a[i] = 0.f;
        const float* wk = Wk + (size_t)h * DH_ * C_ + t;
#pragma unroll 4
        for (int d = 0; d < DH_; ++d) {
            float w = wk[(size_t)d * C_];
#pragma unroll
            for (int i = 0; i < 4; ++i) a[i] += qrow[i][h * DH_ + d] * w;
        }
#pragma unroll
        for (int i = 0; i < 4; ++i) {
            size_t o = ((size_t)(b * H_ + h) * N_ + n0 + i) * C_ + t;
            float v = a[i];
            qk[o] = v;
            qkh[o] = f2h(v);
        }
    }
}

// ---------------------------------------------------------------------------
// K2: logits via SINGLE f16 MFMA pass + argmax. 64n x 256 tokens,
// XOR-swizzled LDS quarters (layout identical to verified bf16 version).
// f16 (11 mantissa bits) makes diff-error ~7e-4 sigma; TAU=6e-3 (~10 sigma)
// flags near-ties for exact full-column fixup.
// ---------------------------------------------------------------------------
__global__ __launch_bounds__(256) void attn_kernel(const unsigned short* __restrict__ qkh,
                                                   const unsigned short* __restrict__ kh,
                                                   unsigned int* __restrict__ idx,
                                                   unsigned int* __restrict__ flag_cnt,
                                                   unsigned int* __restrict__ flag_list) {
    __shared__ __align__(16) unsigned short sA[64 * 32];    //  4 KB
    __shared__ __align__(16) unsigned short sB[256 * 32];   // 16 KB
    int tid = threadIdx.x;
    int w = tid >> 6, l = tid & 63;
    int wm = w >> 1, wn = w & 1;
    int q4 = l >> 4, lm = l & 15;
    int s0 = blockIdx.x * 256;
    int h = blockIdx.y, b = blockIdx.z;
    size_t kbK = ((size_t)b * S_ + s0) * C_;
    size_t kbA = (size_t)(b * H_ + h) * N_ * C_;
    int trow16 = l >> 2;
    int tquart = ((l & 3) ^ ((l >> 3) & 3)) * 8;   // swizzled source quarter
    int sw = (q4 ^ ((lm >> 1) & 3)) * 8;           // swizzled read quarter

    f32x4 acc[2][8];
#pragma unroll
    for (int tm = 0; tm < 2; ++tm)
#pragma unroll
        for (int nt = 0; nt < 8; ++nt) acc[tm][nt] = (f32x4)0.f;

    for (int kc = 0; kc < C_; kc += 32) {
        __syncthreads();
#pragma unroll
        for (int i = 0; i < 5; ++i) {
            int gid = w * 5 + i;
            if (gid < 16) {
                gl_lds16(kh + kbK + (size_t)(gid * 16 + trow16) * C_ + kc + tquart,
                         (char*)sB + gid * 1024);
            } else {
                int g2 = gid - 16;
                gl_lds16(qkh + kbA + (size_t)(g2 * 16 + trow16) * C_ + kc + tquart,
                         (char*)sA + g2 * 1024);
            }
        }
        __syncthreads();
        f16x8 af[2];
#pragma unroll
        for (int tm = 0; tm < 2; ++tm)
            af[tm] = *(const f16x8*)&sA[(wm * 32 + tm * 16 + lm) * 32 + sw];
#pragma unroll
        for (int nt = 0; nt < 8; ++nt) {
            f16x8 bf = *(const f16x8*)&sB[((wn * 8 + nt) * 16 + lm) * 32 + sw];
#pragma unroll
            for (int tm = 0; tm < 2; ++tm)
                acc[tm][nt] = __builtin_amdgcn_mfma_f32_16x16x32_f16(af[tm], bf, acc[tm][nt], 0, 0, 0);
        }
    }
    __syncthreads();

    float* rm1 = (float*)sB;            // [2][256]
    float* rm2 = rm1 + 512;
    int* ri1 = (int*)(rm2 + 512);
    int* ri2 = ri1 + 512;

#pragma unroll
    for (int nt = 0; nt < 8; ++nt) {
        float m1 = -3.4e38f, m2 = -3.4e38f; int i1 = 0, i2 = 0;
#pragma unroll
        for (int tm = 0; tm < 2; ++tm)
#pragma unroll
            for (int r = 0; r < 4; ++r) {
                float v = acc[tm][nt][r];
                int row = wm * 32 + tm * 16 + q4 * 4 + r;
                if (v > m1) { m2 = m1; i2 = i1; m1 = v; i1 = row; }
                else if (v > m2) { m2 = v; i2 = row; }
            }
#pragma unroll
        for (int off = 16; off < 64; off <<= 1) {
            float om1 = __shfl_xor(m1, off), om2 = __shfl_xor(m2, off);
            int oi1 = __shfl_xor(i1, off), oi2 = __shfl_xor(i2, off);
            bool take = (om1 > m1) || (om1 == m1 && oi1 < i1);
            float w1 = take ? om1 : m1; int wi1 = take ? oi1 : i1;
            float l1 = take ? m1 : om1; int li1 = take ? i1 : oi1;
            float s2 = m2; int si2 = i2;
            if (om2 > s2) { s2 = om2; si2 = oi2; }
            if (l1 > s2) { s2 = l1; si2 = li1; }
            m1 = w1; i1 = wi1; m2 = s2; i2 = si2;
        }
        if (q4 == 0) {
            int cw = (wn * 8 + nt) * 16 + lm;
            rm1[wm * 256 + cw] = m1; rm2[wm * 256 + cw] = m2;
            ri1[wm * 256 + cw] = i1; ri2[wm * 256 + cw] = i2;
        }
    }
    __syncthreads();
    float a1 = rm1[tid], a2 = rm2[tid];
    int ai1 = ri1[tid];
    float b1 = rm1[256 + tid], b2 = rm2[256 + tid];
    int bi1 = ri1[256 + tid];
    float w1, s2; int wi1;
    if (b1 > a1) { w1 = b1; wi1 = bi1; s2 = (a1 > b2) ? a1 : b2; }
    else         { w1 = a1; wi1 = ai1; s2 = (a2 > b1) ? a2 : b1; }
    idx[(size_t)(b * H_ + h) * S_ + s0 + tid] = (unsigned)wi1;
    if (w1 - s2 < TAU_) {
        unsigned p = atomicAdd(flag_cnt, 1u);
        if (p < LISTCAP) {
            flag_list[p] = (unsigned)((b * H_ + h) * S_ + s0 + tid);
        }
    }
}

// ---------------------------------------------------------------------------
// K3: fixup — exact fp32 FULL-COLUMN recompute for flagged tokens.
// One wave per token; lane n = group row n; wave argmax, first-index ties.
// ---------------------------------------------------------------------------
__global__ __launch_bounds__(256) void fixup_kernel(const float* __restrict__ qk,
                                                    const float* __restrict__ key,
                                                    const unsigned int* __restrict__ flag_list,
                                                    const unsigned int* __restrict__ flag_cnt,
                                                    unsigned int* __restrict__ idx) {
    int w = threadIdx.x >> 6, l = threadIdx.x & 63;
    unsigned total = flag_cnt[0];
    if (total > LISTCAP) total = LISTCAP;
    for (unsigned t = blockIdx.x * 4 + w; t < total; t += gridDim.x * 4) {
        unsigned tok = flag_list[t] & 0x7FFFFu;
        unsigned bh = tok >> 12;
        unsigned s = tok & 4095u;
        unsigned bb = bh / H_;
        const float* qrow = qk + ((size_t)bh * N_ + l) * C_;
        const float* krow = key + ((size_t)bb * S_ + s) * C_;
        float sum = 0.f;
#pragma unroll 8
        for (int c = 0; c < C_; c += 4) {
            float4 a = *(const float4*)(qrow + c);
            float4 k = *(const float4*)(krow + c);
            sum += a.x * k.x + a.y * k.y + a.z * k.z + a.w * k.w;
        }
        float best = sum; int bi = l;
#pragma unroll
        for (int off = 1; off < 64; off <<= 1) {
            float ob = __shfl_xor(best, off);
            int oi = __shfl_xor(bi, off);
            if (ob > best || (ob == best && oi < bi)) { best = ob; bi = oi; }
        }
        if (l == 0) idx[(size_t)bh * S_ + s] = (unsigned)bi;
    }
}

// ---------------------------------------------------------------------------
// K4: hist_build — per (b,h): histogram -> scan -> counting-sort placement
// ---------------------------------------------------------------------------
__global__ __launch_bounds__(256) void hist_build_kernel(const unsigned int* __restrict__ idx,
                                                         unsigned int* __restrict__ offs,
                                                         unsigned int* __restrict__ order) {
    __shared__ unsigned int cnts[N_];
    __shared__ unsigned int pos[N_];
    int tid = threadIdx.x;
    int bh = blockIdx.x;
    if (tid < N_) cnts[tid] = 0u;
    __syncthreads();
    const unsigned int* idxp = idx + (size_t)bh * S_;
    for (int s = tid; s < S_; s += 256) atomicAdd(&cnts[idxp[s]], 1u);
    __syncthreads();
    if (tid < N_) {
        unsigned v = cnts[tid];
        unsigned x = v;
#pragma unroll
        for (int off = 1; off < 64; off <<= 1) {
            unsigned y = __shfl_up(x, off);
            if (tid >= off) x += y;
        }
        unsigned excl = x - v;
        pos[tid] = excl;
        offs[(size_t)bh * 65 + tid] = excl;
        if (tid == 63) offs[(size_t)bh * 65 + 64] = x;   // == S_
    }
    __syncthreads();
    unsigned int* op = order + (size_t)bh * S_;
    for (int s = tid; s < S_; s += 256) {
        unsigned g = idxp[s];
        unsigned p = atomicAdd(&pos[g], 1u);
        op[p] = (unsigned)s;
    }
}

// ---------------------------------------------------------------------------
// K5: agg2 — per (group, half): contiguous token list -> register accumulation
// (now reads f16 kh: more accurate group sums than bf16)
// ---------------------------------------------------------------------------
__global__ __launch_bounds__(256) void agg2_kernel(const unsigned short* __restrict__ kh,
                                                   const unsigned int* __restrict__ order,
                                                   const unsigned int* __restrict__ offs,
                                                   float* __restrict__ gpart) {
    int tid = threadIdx.x;
    int w = tid >> 6, l = tid & 63;
    int h = blockIdx.y, b = blockIdx.z;
    int bh = b * H_ + h;
    int wid = blockIdx.x * 4 + w;       // 0..127
    int g = wid >> 1, part = wid & 1;
    unsigned beg = offs[(size_t)bh * 65 + g];
    unsigned end = offs[(size_t)bh * 65 + g + 1];
    int cnt = (int)(end - beg);
    float inv = 1.f / ((float)cnt + 1.f);
    const unsigned int* op = order + (size_t)bh * S_ + beg;
    const unsigned int* kbase = (const unsigned int*)(kh + (size_t)b * S_ * C_);
    float a0 = 0.f, a1 = 0.f, a2 = 0.f, a3 = 0.f, a4 = 0.f, a5 = 0.f;
    for (int base = part * 64; base < cnt; base += 128) {
        int m = cnt - base; if (m > 64) m = 64;
        unsigned sv = (l < m) ? op[base + l] : 0u;
        for (int i = 0; i < m; ++i) {
            int s = (int)__shfl((int)sv, i);
            const unsigned int* kp = kbase + (size_t)s * (C_ / 2) + l * 3;
            unsigned u0 = kp[0], u1 = kp[1], u2 = kp[2];
            a0 += h2f_lo(u0); a1 += h2f_hi(u0);
            a2 += h2f_lo(u1); a3 += h2f_hi(u1);
            a4 += h2f_lo(u2); a5 += h2f_hi(u2);
        }
    }
    float* gp = gpart + (((size_t)bh * 2 + part) * N_ + g) * C_ + l * 6;
    float2 o0 = { a0 * inv, a1 * inv };
    float2 o1 = { a2 * inv, a3 * inv };
    float2 o2 = { a4 * inv, a5 * inv };
    ((float2*)gp)[0] = o0; ((float2*)gp)[1] = o1; ((float2*)gp)[2] = o2;
}

// ---------------------------------------------------------------------------
// K6: gv — one wave per (bh, group); lane d: dot(row, Wv[h*64+d])
// ---------------------------------------------------------------------------
__global__ __launch_bounds__(256) void gv_kernel(const float* __restrict__ gpart,
                                                 const float* __restrict__ Wv,
                                                 float* __restrict__ gvn) {
    __shared__ float rows[4][C_];
    int tid = threadIdx.x;
    int w = tid >> 6, l = tid & 63;
    int h = blockIdx.y, b = blockIdx.z;
    int bh = b * H_ + h;
    int g = blockIdx.x * 4 + w;
    const float* s0 = gpart + (((size_t)bh * 2 + 0) * N_ + g) * C_;
    const float* s1 = gpart + (((size_t)bh * 2 + 1) * N_ + g) * C_;
    for (int i = l; i < C_ / 4; i += 64) {
        float4 x = ((const float4*)s0)[i];
        float4 y = ((const float4*)s1)[i];
        float4 z = { x.x + y.x, x.y + y.y, x.z + y.z, x.w + y.w };
        *(float4*)&rows[w][i * 4] = z;
    }
    __syncthreads();
    const float* wrow = Wv + (size_t)(h * DH_ + l) * C_;
    float acc = 0.f;
#pragma unroll 8
    for (int c4 = 0; c4 < C_ / 4; ++c4) {
        float4 a = *(const float4*)&rows[w][c4 * 4];
        float4 wv = *(const float4*)&wrow[c4 * 4];
        acc += a.x * wv.x + a.y * wv.y + a.z * wv.z + a.w * wv.w;
    }
    gvn[((size_t)bh * N_ + g) * DH_ + l] = acc;
}

// ---------------------------------------------------------------------------
// K7: out — 2 rows per block (halves Wp L2 traffic vs 1 row/block)
// ---------------------------------------------------------------------------
__global__ __launch_bounds__(384) void out_kernel(const float* __restrict__ gvn,
                                                  const float* __restrict__ Wp,
                                                  const float* __restrict__ bp,
                                                  float* __restrict__ out) {
    __shared__ float vals[2][C_];
    int bn0 = blockIdx.x * 2;
    int b = bn0 >> 6, n0 = bn0 & 63;
    int t = threadIdx.x;
    int h = t >> 6, d = t & 63;
#pragma unroll
    for (int i = 0; i < 2; ++i)
        vals[i][t] = gvn[((size_t)(b * H_ + h) * N_ + n0 + i) * DH_ + d];
    __syncthreads();
    const float4* w4 = (const float4*)(Wp + (size_t)t * C_);
    float s0 = bp[t], s1 = s0;
#pragma unroll 8
    for (int i = 0; i < C_ / 4; ++i) {
        float4 w = w4[i];
        float4 a = ((const float4*)vals[0])[i];
        float4 c = ((const float4*)vals[1])[i];
        s0 += a.x * w.x + a.y * w.y + a.z * w.z + a.w * w.w;
        s1 += c.x * w.x + c.y * w.y + c.z * w.z + c.w * w.w;
    }
    out[((size_t)(b * N_ + n0)) * C_ + t] = s0;
    out[((size_t)(b * N_ + n0 + 1)) * C_ + t] = s1;
}

// ---------------------------------------------------------------------------
extern "C" void kernel_launch(void* const* d_in, const int* in_sizes, int n_in,
                              void* d_out, int out_size, void* d_ws, size_t ws_size,
                              hipStream_t stream) {
    (void)in_sizes; (void)n_in; (void)out_size; (void)ws_size;
    const float* query = (const float*)d_in[0];
    const float* key   = (const float*)d_in[1];
    const float* Wq    = (const float*)d_in[2];
    const float* Wk    = (const float*)d_in[3];
    const float* Wv    = (const float*)d_in[4];
    const float* Wp    = (const float*)d_in[5];
    const float* bp    = (const float*)d_in[6];
    float* out = (float*)d_out;

    char* ws = (char*)d_ws;
    size_t off = 0;
    unsigned short* kh   = (unsigned short*)(ws + off); off += (size_t)B_ * S_ * C_ * 2;          // 50.3 MB
    float* qk            = (float*)(ws + off);          off += (size_t)B_ * H_ * N_ * C_ * 4;     //  9.4 MB
    unsigned short* qkh  = (unsigned short*)(ws + off); off += (size_t)B_ * H_ * N_ * C_ * 2;     //  4.7 MB
    unsigned int* idx    = (unsigned int*)(ws + off);   off += (size_t)B_ * H_ * S_ * 4;
    unsigned int* order  = (unsigned int*)(ws + off);   off += (size_t)B_ * H_ * S_ * 4;
    unsigned int* offs   = (unsigned int*)(ws + off);   off += (size_t)B_ * H_ * 65 * 4;
    float* gpart         = (float*)(ws + off);          off += (size_t)B_ * H_ * 2 * N_ * C_ * 4; // 18.9 MB
    float* gvn           = (float*)(ws + off);          off += (size_t)B_ * H_ * N_ * DH_ * 4;
    unsigned int* fcnt   = (unsigned int*)(ws + off);   off += 256;
    unsigned int* flist  = (unsigned int*)(ws + off);   off += (size_t)LISTCAP * 4;

    hipMemsetAsync(fcnt, 0, 256, stream);

    prep_kernel<<<(B_ * S_ * C_ / 8) / 256, 256, 0, stream>>>(key, kh);
    qk_fused_kernel<<<dim3(N_ / 4, B_), 384, 0, stream>>>(query, Wq, Wk, qk, qkh);
    attn_kernel<<<dim3(S_ / 256, H_, B_), 256, 0, stream>>>(qkh, kh, idx, fcnt, flist);
    fixup_kernel<<<256, 256, 0, stream>>>(qk, key, flist, fcnt, idx);
    hist_build_kernel<<<B_ * H_, 256, 0, stream>>>(idx, offs, order);
    agg2_kernel<<<dim3(32, H_, B_), 256, 0, stream>>>(kh, order, offs, gpart);
    gv_kernel<<<dim3(16, H_, B_), 256, 0, stream>>>(gpart, Wv, gvn);
    out_kernel<<<B_ * N_ / 2, 384, 0, stream>>>(gvn, Wp, bp, out);
}